// Round 1
// baseline (782.491 us; speedup 1.0000x reference)
//
#include <hip/hip_runtime.h>

#define HH 256
#define WW 256
#define HW (HH * WW)
#define NB 8
#define NPTS 65536
#define EPSW 1e-5f
#define BIGF 1e10f

// Fill z-buffer with +BIG (as uint bits) and zero the depth/weight outputs.
__global__ void init_k(unsigned int* __restrict__ zbuf,
                       float* __restrict__ depth, float* __restrict__ weight) {
    int i = blockIdx.x * blockDim.x + threadIdx.x;
    if (i < NB * HW) {
        zbuf[i] = __float_as_uint(BIGF);
        depth[i] = 0.0f;
        weight[i] = 0.0f;
    }
}

// Scatter-min depth over 5x5 patch. Positive floats: uint order == float order.
__global__ void zmin_k(const float* __restrict__ pts, unsigned int* __restrict__ zbuf) {
    int i = blockIdx.x * blockDim.x + threadIdx.x;  // b*N + n
    if (i >= NB * NPTS) return;
    float x = pts[i * 3 + 0];
    float y = pts[i * 3 + 1];
    float z = pts[i * 3 + 2];
    int px = __float2int_rn(x);   // round-half-even, matches jnp.round
    int py = __float2int_rn(y);
    unsigned int zb = __float_as_uint(z);
    int b = i / NPTS;
    unsigned int* zb_b = zbuf + b * HW;
    #pragma unroll
    for (int di = -2; di <= 2; ++di) {
        int ii = py + di;
        if (ii < 0 || ii >= HH) continue;
        #pragma unroll
        for (int dj = -2; dj <= 2; ++dj) {
            int jj = px + dj;
            if (jj < 0 || jj >= WW) continue;
            atomicMin(&zb_b[ii * WW + jj], zb);
        }
    }
}

// Visibility + weighted splat over 7x7 patch.
__global__ void splat_k(const float* __restrict__ pts,
                        const unsigned int* __restrict__ zbuf,
                        const float* __restrict__ thr_p,
                        float* __restrict__ depth, float* __restrict__ weight,
                        float* __restrict__ vis) {
    int i = blockIdx.x * blockDim.x + threadIdx.x;
    if (i >= NB * NPTS) return;
    float x = pts[i * 3 + 0];
    float y = pts[i * 3 + 1];
    float z = pts[i * 3 + 2];
    int px = __float2int_rn(x);
    int py = __float2int_rn(y);
    int b = i / NPTS;
    bool in_img = (px >= 0) && (px < WW) && (py >= 0) && (py < HH);
    bool visible = false;
    if (in_img) {
        float zmin = __uint_as_float(zbuf[b * HW + py * WW + px]);
        float thr = *thr_p;
        visible = (z <= zmin + thr);
    }
    vis[i] = visible ? 1.0f : 0.0f;
    if (!visible) return;
    float* dep_b = depth + b * HW;
    float* wei_b = weight + b * HW;
    #pragma unroll
    for (int di = -3; di <= 3; ++di) {
        int ii = py + di;
        if (ii < 0 || ii >= HH) continue;
        float dy = y - (float)ii;
        #pragma unroll
        for (int dj = -3; dj <= 3; ++dj) {
            int jj = px + dj;
            if (jj < 0 || jj >= WW) continue;
            float dx = x - (float)jj;
            float d2 = dx * dx + dy * dy;
            float w = 1.0f / (d2 + EPSW);
            atomicAdd(&dep_b[ii * WW + jj], w * z);
            atomicAdd(&wei_b[ii * WW + jj], w);
        }
    }
}

extern "C" void kernel_launch(void* const* d_in, const int* in_sizes, int n_in,
                              void* d_out, int out_size, void* d_ws, size_t ws_size,
                              hipStream_t stream) {
    const float* pts   = (const float*)d_in[0];   // [B, N, 3]
    const float* thr_p = (const float*)d_in[1];   // scalar

    float* depth  = (float*)d_out;                 // [B*H*W]
    float* weight = depth + NB * HW;               // [B*H*W]
    float* vis    = weight + NB * HW;              // [B*N]

    unsigned int* zbuf = (unsigned int*)d_ws;      // [B*H*W] uint-as-float

    const int threads = 256;
    int grid_img = (NB * HW + threads - 1) / threads;
    int grid_pts = (NB * NPTS + threads - 1) / threads;

    init_k<<<grid_img, threads, 0, stream>>>(zbuf, depth, weight);
    zmin_k<<<grid_pts, threads, 0, stream>>>(pts, zbuf);
    splat_k<<<grid_pts, threads, 0, stream>>>(pts, zbuf, thr_p, depth, weight, vis);
}

// Round 2
// 318.658 us; speedup vs baseline: 2.4556x; 2.4556x over previous
//
#include <hip/hip_runtime.h>

#define HH 256
#define WW 256
#define HW (HH * WW)
#define NB 8
#define NPTS 65536
#define EPSW 1e-5f
#define BIGF 1e10f

// Fill own-pixel z-buffer with +BIG (as uint bits) and zero the depth/weight outputs.
__global__ void init_k(unsigned int* __restrict__ zown,
                       float* __restrict__ depth, float* __restrict__ weight) {
    int i = blockIdx.x * blockDim.x + threadIdx.x;
    if (i < NB * HW) {
        zown[i] = __float_as_uint(BIGF);
        depth[i] = 0.0f;
        weight[i] = 0.0f;
    }
}

// 1 atomicMin per point at its OWN pixel only (all points round in-image since
// x in [0, W-1), y in [0, H-1)). Positive floats: uint order == float order.
__global__ void scatter_k(const float* __restrict__ pts, unsigned int* __restrict__ zown) {
    int i = blockIdx.x * blockDim.x + threadIdx.x;  // b*N + n
    if (i >= NB * NPTS) return;
    float x = pts[i * 3 + 0];
    float y = pts[i * 3 + 1];
    float z = pts[i * 3 + 2];
    int px = __float2int_rn(x);   // round-half-even, matches jnp.round
    int py = __float2int_rn(y);
    int b = i / NPTS;
    // Guard anyway (cheap) in case of boundary rounding.
    if (px >= 0 && px < WW && py >= 0 && py < HH)
        atomicMin(&zown[b * HW + py * WW + px], __float_as_uint(z));
}

// Dense 5x5 sliding-window min: zbuf[i,j] = min over win5x5 of zown.
// Exactly equivalent to the reference's 5x5 scatter-min patch.
__global__ void winmin_k(const unsigned int* __restrict__ zown, float* __restrict__ zbuf) {
    int idx = blockIdx.x * blockDim.x + threadIdx.x;
    if (idx >= NB * HW) return;
    int j = idx & (WW - 1);
    int i = (idx >> 8) & (HH - 1);
    const unsigned int* zo = zown + (idx & ~(HW - 1));  // batch base
    float m = BIGF;
    #pragma unroll
    for (int di = -2; di <= 2; ++di) {
        int ii = i + di;
        if (ii < 0 || ii >= HH) continue;
        const unsigned int* row = zo + ii * WW;
        #pragma unroll
        for (int dj = -2; dj <= 2; ++dj) {
            int jj = j + dj;
            if (jj < 0 || jj >= WW) continue;
            m = fminf(m, __uint_as_float(row[jj]));
        }
    }
    zbuf[idx] = m;
}

// Visibility + weighted splat over 7x7 patch.
__global__ void splat_k(const float* __restrict__ pts,
                        const float* __restrict__ zbuf,
                        const float* __restrict__ thr_p,
                        float* __restrict__ depth, float* __restrict__ weight,
                        float* __restrict__ vis) {
    int i = blockIdx.x * blockDim.x + threadIdx.x;
    if (i >= NB * NPTS) return;
    float x = pts[i * 3 + 0];
    float y = pts[i * 3 + 1];
    float z = pts[i * 3 + 2];
    int px = __float2int_rn(x);
    int py = __float2int_rn(y);
    int b = i / NPTS;
    bool in_img = (px >= 0) && (px < WW) && (py >= 0) && (py < HH);
    bool visible = false;
    if (in_img) {
        float zmin = zbuf[b * HW + py * WW + px];
        float thr = *thr_p;
        visible = (z <= zmin + thr);
    }
    vis[i] = visible ? 1.0f : 0.0f;
    if (!visible) return;
    float* dep_b = depth + b * HW;
    float* wei_b = weight + b * HW;
    #pragma unroll
    for (int di = -3; di <= 3; ++di) {
        int ii = py + di;
        if (ii < 0 || ii >= HH) continue;
        float dy = y - (float)ii;
        #pragma unroll
        for (int dj = -3; dj <= 3; ++dj) {
            int jj = px + dj;
            if (jj < 0 || jj >= WW) continue;
            float dx = x - (float)jj;
            float d2 = dx * dx + dy * dy;
            float w = 1.0f / (d2 + EPSW);
            atomicAdd(&dep_b[ii * WW + jj], w * z);
            atomicAdd(&wei_b[ii * WW + jj], w);
        }
    }
}

extern "C" void kernel_launch(void* const* d_in, const int* in_sizes, int n_in,
                              void* d_out, int out_size, void* d_ws, size_t ws_size,
                              hipStream_t stream) {
    const float* pts   = (const float*)d_in[0];   // [B, N, 3]
    const float* thr_p = (const float*)d_in[1];   // scalar

    float* depth  = (float*)d_out;                 // [B*H*W]
    float* weight = depth + NB * HW;               // [B*H*W]
    float* vis    = weight + NB * HW;              // [B*N]

    unsigned int* zown = (unsigned int*)d_ws;      // [B*H*W] own-pixel min (uint bits)
    float* zbuf = (float*)(zown + NB * HW);        // [B*H*W] 5x5 window min

    const int threads = 256;
    int grid_img = (NB * HW + threads - 1) / threads;
    int grid_pts = (NB * NPTS + threads - 1) / threads;

    init_k<<<grid_img, threads, 0, stream>>>(zown, depth, weight);
    scatter_k<<<grid_pts, threads, 0, stream>>>(pts, zown);
    winmin_k<<<grid_img, threads, 0, stream>>>(zown, zbuf);
    splat_k<<<grid_pts, threads, 0, stream>>>(pts, zbuf, thr_p, depth, weight, vis);
}

// Round 3
// 170.939 us; speedup vs baseline: 4.5776x; 1.8642x over previous
//
#include <hip/hip_runtime.h>

#define HH 256
#define WW 256
#define HW (HH * WW)
#define NB 8
#define NPTS 65536
#define EPSW 1e-5f
#define BIGF 1e10f

#define TS 32                 // tile side (pixels)
#define TPS 8                 // tiles per side (256/32)
#define NTILES (NB * TPS * TPS)   // 512
#define CAP 2048              // max entries per tile list

// Init: own-pixel z-buffer to +BIG bits; tile counters to 0.
__global__ void init_k(unsigned int* __restrict__ zown, unsigned int* __restrict__ counts) {
    int i = blockIdx.x * blockDim.x + threadIdx.x;
    if (i < NB * HW) zown[i] = __float_as_uint(BIGF);
    if (i < NTILES) counts[i] = 0u;
}

// 1 atomicMin per point at its own pixel. Positive floats: uint order == float order.
__global__ void scatter_k(const float* __restrict__ pts, unsigned int* __restrict__ zown) {
    int i = blockIdx.x * blockDim.x + threadIdx.x;  // b*N + n
    if (i >= NB * NPTS) return;
    float x = pts[i * 3 + 0];
    float y = pts[i * 3 + 1];
    float z = pts[i * 3 + 2];
    int px = __float2int_rn(x);   // round-half-even, matches jnp.round
    int py = __float2int_rn(y);
    int b = i / NPTS;
    if (px >= 0 && px < WW && py >= 0 && py < HH)
        atomicMin(&zown[b * HW + py * WW + px], __float_as_uint(z));
}

// Dense 5x5 sliding-window min over zown -> zbuf (exactly = 5x5 scatter-min).
__global__ void winmin_k(const unsigned int* __restrict__ zown, float* __restrict__ zbuf) {
    int idx = blockIdx.x * blockDim.x + threadIdx.x;
    if (idx >= NB * HW) return;
    int j = idx & (WW - 1);
    int i = (idx >> 8) & (HH - 1);
    const unsigned int* zo = zown + (idx & ~(HW - 1));
    float m = BIGF;
    #pragma unroll
    for (int di = -2; di <= 2; ++di) {
        int ii = i + di;
        if (ii < 0 || ii >= HH) continue;
        const unsigned int* row = zo + ii * WW;
        #pragma unroll
        for (int dj = -2; dj <= 2; ++dj) {
            int jj = j + dj;
            if (jj < 0 || jj >= WW) continue;
            m = fminf(m, __uint_as_float(row[jj]));
        }
    }
    zbuf[idx] = m;
}

// Visibility + push visible point index into each tile its 7x7 patch touches.
__global__ void vis_bin_k(const float* __restrict__ pts, const float* __restrict__ zbuf,
                          const float* __restrict__ thr_p, float* __restrict__ vis,
                          unsigned int* __restrict__ counts, unsigned int* __restrict__ entries) {
    int i = blockIdx.x * blockDim.x + threadIdx.x;
    if (i >= NB * NPTS) return;
    float x = pts[i * 3 + 0];
    float y = pts[i * 3 + 1];
    float z = pts[i * 3 + 2];
    int px = __float2int_rn(x);
    int py = __float2int_rn(y);
    int b = i / NPTS;
    bool in_img = (px >= 0) && (px < WW) && (py >= 0) && (py < HH);
    bool visible = false;
    if (in_img) {
        float zmin = zbuf[b * HW + py * WW + px];
        visible = (z <= zmin + *thr_p);
    }
    vis[i] = visible ? 1.0f : 0.0f;
    if (!visible) return;
    int tx0 = max((px - 3) >> 5, 0), tx1 = min((px + 3) >> 5, TPS - 1);
    int ty0 = max((py - 3) >> 5, 0), ty1 = min((py + 3) >> 5, TPS - 1);
    for (int ty = ty0; ty <= ty1; ++ty)
        for (int tx = tx0; tx <= tx1; ++tx) {
            int tile = b * (TPS * TPS) + ty * TPS + tx;
            unsigned int pos = atomicAdd(&counts[tile], 1u);
            if (pos < CAP) entries[tile * CAP + pos] = (unsigned int)i;
        }
}

// One workgroup per 32x32 tile: LDS-accumulate the splat, then dense stores.
__global__ void __launch_bounds__(256) splat_tile_k(
        const float* __restrict__ pts,
        const unsigned int* __restrict__ counts, const unsigned int* __restrict__ entries,
        float* __restrict__ depth, float* __restrict__ weight) {
    __shared__ float sdep[TS * TS];
    __shared__ float swei[TS * TS];
    int tile = blockIdx.x;
    int b  = tile >> 6;
    int ty = (tile >> 3) & 7;
    int tx = tile & 7;
    int base_i = ty * TS, base_j = tx * TS;

    for (int t = threadIdx.x; t < TS * TS; t += blockDim.x) { sdep[t] = 0.0f; swei[t] = 0.0f; }
    __syncthreads();

    unsigned int cnt = counts[tile];
    if (cnt > CAP) cnt = CAP;
    for (unsigned int e = threadIdx.x; e < cnt; e += blockDim.x) {
        unsigned int idx = entries[tile * CAP + e];
        float x = pts[idx * 3 + 0];
        float y = pts[idx * 3 + 1];
        float z = pts[idx * 3 + 2];
        int px = __float2int_rn(x);
        int py = __float2int_rn(y);
        #pragma unroll
        for (int di = -3; di <= 3; ++di) {
            int ii = py + di;
            int li = ii - base_i;
            if (li < 0 || li >= TS) continue;
            float dy = y - (float)ii;
            #pragma unroll
            for (int dj = -3; dj <= 3; ++dj) {
                int jj = px + dj;
                int lj = jj - base_j;
                if (lj < 0 || lj >= TS) continue;
                float dx = x - (float)jj;
                float w = 1.0f / (dx * dx + dy * dy + EPSW);
                atomicAdd(&sdep[li * TS + lj], w * z);
                atomicAdd(&swei[li * TS + lj], w);
            }
        }
    }
    __syncthreads();

    for (int t = threadIdx.x; t < TS * TS; t += blockDim.x) {
        int li = t >> 5, lj = t & 31;
        int g = b * HW + (base_i + li) * WW + (base_j + lj);
        depth[g]  = sdep[t];
        weight[g] = swei[t];
    }
}

extern "C" void kernel_launch(void* const* d_in, const int* in_sizes, int n_in,
                              void* d_out, int out_size, void* d_ws, size_t ws_size,
                              hipStream_t stream) {
    const float* pts   = (const float*)d_in[0];   // [B, N, 3]
    const float* thr_p = (const float*)d_in[1];   // scalar

    float* depth  = (float*)d_out;                 // [B*H*W]
    float* weight = depth + NB * HW;               // [B*H*W]
    float* vis    = weight + NB * HW;              // [B*N]

    unsigned int* zown    = (unsigned int*)d_ws;             // [B*H*W]
    float*        zbuf    = (float*)(zown + NB * HW);        // [B*H*W]
    unsigned int* counts  = (unsigned int*)(zbuf + NB * HW); // [NTILES]
    unsigned int* entries = counts + NTILES;                 // [NTILES*CAP]

    const int threads = 256;
    int grid_img = (NB * HW + threads - 1) / threads;
    int grid_pts = (NB * NPTS + threads - 1) / threads;

    init_k<<<grid_img, threads, 0, stream>>>(zown, counts);
    scatter_k<<<grid_pts, threads, 0, stream>>>(pts, zown);
    winmin_k<<<grid_img, threads, 0, stream>>>(zown, zbuf);
    vis_bin_k<<<grid_pts, threads, 0, stream>>>(pts, zbuf, thr_p, vis, counts, entries);
    splat_tile_k<<<NTILES, threads, 0, stream>>>(pts, counts, entries, depth, weight);
}

// Round 4
// 131.278 us; speedup vs baseline: 5.9606x; 1.3021x over previous
//
#include <hip/hip_runtime.h>

#define HH 256
#define WW 256
#define HW (HH * WW)
#define NB 8
#define NPTS 65536
#define EPSW 1e-5f
#define BIGF 1e10f

#define TS 32                     // tile side (pixels)
#define TPS 8                     // tiles per side (256/32)
#define NTILES (NB * TPS * TPS)   // 512
#define NREP 4                    // counter/list replicas (contention /4)
#define SEGCAP 256                // entries per tile per replica (avg ~32 expected)

// Init: own-pixel z-buffer to +BIG bits; replica tile counters to 0.
__global__ void init_k(unsigned int* __restrict__ zown, unsigned int* __restrict__ counts) {
    int i = blockIdx.x * blockDim.x + threadIdx.x;
    if (i < NB * HW) zown[i] = __float_as_uint(BIGF);
    if (i < NREP * NTILES) counts[i] = 0u;
}

// 4 points per thread; 1 atomicMin per point at its own pixel.
__global__ void scatter_k(const float4* __restrict__ pts4, unsigned int* __restrict__ zown) {
    int t = blockIdx.x * blockDim.x + threadIdx.x;           // handles points 4t..4t+3
    if (t >= NB * NPTS / 4) return;
    float4 v0 = pts4[3 * t + 0];
    float4 v1 = pts4[3 * t + 1];
    float4 v2 = pts4[3 * t + 2];
    float xs[4] = {v0.x, v0.w, v1.z, v2.y};
    float ys[4] = {v0.y, v1.x, v1.w, v2.z};
    float zs[4] = {v0.z, v1.y, v2.x, v2.w};
    #pragma unroll
    for (int k = 0; k < 4; ++k) {
        int i = 4 * t + k;
        int px = __float2int_rn(xs[k]);   // round-half-even, matches jnp.round
        int py = __float2int_rn(ys[k]);
        int b = i / NPTS;
        if (px >= 0 && px < WW && py >= 0 && py < HH)
            atomicMin(&zown[b * HW + py * WW + px], __float_as_uint(zs[k]));
    }
}

// Dense 5x5 sliding-window min over zown -> zbuf (exactly = 5x5 scatter-min).
__global__ void winmin_k(const unsigned int* __restrict__ zown, float* __restrict__ zbuf) {
    int idx = blockIdx.x * blockDim.x + threadIdx.x;
    if (idx >= NB * HW) return;
    int j = idx & (WW - 1);
    int i = (idx >> 8) & (HH - 1);
    const unsigned int* zo = zown + (idx & ~(HW - 1));
    float m = BIGF;
    #pragma unroll
    for (int di = -2; di <= 2; ++di) {
        int ii = i + di;
        if (ii < 0 || ii >= HH) continue;
        const unsigned int* row = zo + ii * WW;
        #pragma unroll
        for (int dj = -2; dj <= 2; ++dj) {
            int jj = j + dj;
            if (jj < 0 || jj >= WW) continue;
            m = fminf(m, __uint_as_float(row[jj]));
        }
    }
    zbuf[idx] = m;
}

// 4 points per thread: visibility + push (x,y,z) payload into replica tile lists.
__global__ void vis_bin_k(const float4* __restrict__ pts4, const float* __restrict__ zbuf,
                          const float* __restrict__ thr_p, float* __restrict__ vis,
                          unsigned int* __restrict__ counts, float4* __restrict__ entries) {
    int t = blockIdx.x * blockDim.x + threadIdx.x;
    if (t >= NB * NPTS / 4) return;
    float thr = *thr_p;
    int rep = (threadIdx.x >> 6) & (NREP - 1);
    float4 v0 = pts4[3 * t + 0];
    float4 v1 = pts4[3 * t + 1];
    float4 v2 = pts4[3 * t + 2];
    float xs[4] = {v0.x, v0.w, v1.z, v2.y};
    float ys[4] = {v0.y, v1.x, v1.w, v2.z};
    float zs[4] = {v0.z, v1.y, v2.x, v2.w};
    #pragma unroll
    for (int k = 0; k < 4; ++k) {
        int i = 4 * t + k;
        float x = xs[k], y = ys[k], z = zs[k];
        int px = __float2int_rn(x);
        int py = __float2int_rn(y);
        int b = i / NPTS;
        bool in_img = (px >= 0) && (px < WW) && (py >= 0) && (py < HH);
        bool visible = false;
        if (in_img) {
            float zmin = zbuf[b * HW + py * WW + px];
            visible = (z <= zmin + thr);
        }
        vis[i] = visible ? 1.0f : 0.0f;
        if (!visible) continue;
        int tx0 = max((px - 3) >> 5, 0), tx1 = min((px + 3) >> 5, TPS - 1);
        int ty0 = max((py - 3) >> 5, 0), ty1 = min((py + 3) >> 5, TPS - 1);
        for (int ty = ty0; ty <= ty1; ++ty)
            for (int tx = tx0; tx <= tx1; ++tx) {
                int tile = b * (TPS * TPS) + ty * TPS + tx;
                int seg = rep * NTILES + tile;
                unsigned int pos = atomicAdd(&counts[seg], 1u);
                if (pos < SEGCAP) entries[(size_t)seg * SEGCAP + pos] = make_float4(x, y, z, 0.0f);
            }
    }
}

// One workgroup per 32x32 tile: LDS-accumulate the splat from 4 replica lists,
// then dense coalesced stores (each pixel owned by exactly one tile).
__global__ void __launch_bounds__(256) splat_tile_k(
        const unsigned int* __restrict__ counts, const float4* __restrict__ entries,
        float* __restrict__ depth, float* __restrict__ weight) {
    __shared__ float sdep[TS * TS];
    __shared__ float swei[TS * TS];
    int tile = blockIdx.x;
    int b  = tile >> 6;
    int ty = (tile >> 3) & 7;
    int tx = tile & 7;
    int base_i = ty * TS, base_j = tx * TS;

    for (int t = threadIdx.x; t < TS * TS; t += blockDim.x) { sdep[t] = 0.0f; swei[t] = 0.0f; }
    __syncthreads();

    for (int rep = 0; rep < NREP; ++rep) {
        int seg = rep * NTILES + tile;
        unsigned int cnt = counts[seg];
        if (cnt > SEGCAP) cnt = SEGCAP;
        for (unsigned int e = threadIdx.x; e < cnt; e += blockDim.x) {
            float4 p = entries[(size_t)seg * SEGCAP + e];
            float x = p.x, y = p.y, z = p.z;
            int px = __float2int_rn(x);
            int py = __float2int_rn(y);
            #pragma unroll
            for (int di = -3; di <= 3; ++di) {
                int ii = py + di;
                int li = ii - base_i;
                if (li < 0 || li >= TS) continue;
                float dy = y - (float)ii;
                #pragma unroll
                for (int dj = -3; dj <= 3; ++dj) {
                    int jj = px + dj;
                    int lj = jj - base_j;
                    if (lj < 0 || lj >= TS) continue;
                    float dx = x - (float)jj;
                    float w = 1.0f / (dx * dx + dy * dy + EPSW);
                    atomicAdd(&sdep[li * TS + lj], w * z);
                    atomicAdd(&swei[li * TS + lj], w);
                }
            }
        }
    }
    __syncthreads();

    for (int t = threadIdx.x; t < TS * TS; t += blockDim.x) {
        int li = t >> 5, lj = t & 31;
        int g = b * HW + (base_i + li) * WW + (base_j + lj);
        depth[g]  = sdep[t];
        weight[g] = swei[t];
    }
}

extern "C" void kernel_launch(void* const* d_in, const int* in_sizes, int n_in,
                              void* d_out, int out_size, void* d_ws, size_t ws_size,
                              hipStream_t stream) {
    const float4* pts4 = (const float4*)d_in[0];  // [B, N, 3] viewed as float4[3*N/4]
    const float* thr_p = (const float*)d_in[1];   // scalar

    float* depth  = (float*)d_out;                 // [B*H*W]
    float* weight = depth + NB * HW;               // [B*H*W]
    float* vis    = weight + NB * HW;              // [B*N]

    unsigned int* zown    = (unsigned int*)d_ws;               // [B*H*W]            2 MB
    float*        zbuf    = (float*)(zown + NB * HW);          // [B*H*W]            2 MB
    unsigned int* counts  = (unsigned int*)(zbuf + NB * HW);   // [NREP*NTILES]      8 KB
    float4*       entries = (float4*)(counts + NREP * NTILES); // [NREP*NTILES*SEGCAP] 8.4 MB

    const int threads = 256;
    int grid_img  = (NB * HW + threads - 1) / threads;
    int grid_pts4 = (NB * NPTS / 4 + threads - 1) / threads;

    init_k<<<grid_img, threads, 0, stream>>>(zown, counts);
    scatter_k<<<grid_pts4, threads, 0, stream>>>(pts4, zown);
    winmin_k<<<grid_img, threads, 0, stream>>>(zown, zbuf);
    vis_bin_k<<<grid_pts4, threads, 0, stream>>>(pts4, zbuf, thr_p, vis, counts, entries);
    splat_tile_k<<<NTILES, threads, 0, stream>>>(counts, entries, depth, weight);
}